// Round 20
// baseline (203.133 us; speedup 1.0000x reference)
//
#include <hip/hip_runtime.h>

// Problem constants
#define NDRUG 50000
#define NDIS  50000
#define RR    5
#define FF    128
#define EFFD  128
#define OUTD  64
#define EE    400000
#define NCOL  (RR * OUTD)        // 320 columns in fused OUTPUT layout [n][r*64+o]
#define NEDGE (RR * EE)          // 2,000,000 edges per direction

#define NROWP 50016              // padded rows per rating region (rows 50000..50015 are ZERO)

// Two-level bucket sort
#define NBKT    196              // coarse buckets per (dir,r): dst>>8 (50000/256)
#define CAP     4096             // slot capacity per bucket
#define NGB     (2 * RR * NBKT)  // 1960 global buckets

#define NCHUNKE 128              // edge chunks per r (both dirs handled per block)
#define CHUNKE  (EE / NCHUNKE)   // 3125 edges per chunk (exact)

// merged part+gemm dispatch geometry
#define PART_BLOCKS (NCHUNKE * RR)            // 640
#define GEMM_RB     ((NDRUG + 63) / 64)       // 782 row-blocks
#define GEMM_BLOCKS (GEMM_RB * 4)             // x2 col-half x2 side = 3128
#define PG_BLOCKS   (PART_BLOCKS + GEMM_BLOCKS)

typedef unsigned short ushort_t;
typedef unsigned int uint_t;
typedef short short8 __attribute__((ext_vector_type(8)));
typedef float f32x4 __attribute__((ext_vector_type(4)));
typedef float f32x2 __attribute__((ext_vector_type(2)));

// f32 -> bf16 round-to-nearest-even
static __device__ __forceinline__ ushort_t f2bf(float f) {
    uint_t u = __float_as_uint(f);
    uint_t r = (u + 0x7FFFu + ((u >> 16) & 1u)) >> 16;
    return (ushort_t)r;
}

// ---------------------------------------------------------------------------
// Kernel A: Mt[col][f] = bf16( sum_e (att[r,0]*basis[0,f,e]+att[r,1]*basis[1,f,e]) * fc_w[e,o] )
// ---------------------------------------------------------------------------
__global__ __launch_bounds__(256) void k_make_M(const float* __restrict__ att,
                                                const float* __restrict__ basis,
                                                const float* __restrict__ fcw,
                                                ushort_t* __restrict__ Mt) {
    int tid = blockIdx.x * 256 + threadIdx.x;
    if (tid >= RR * FF * OUTD) return;
    int r = tid / (FF * OUTD);
    int rem = tid - r * FF * OUTD;
    int f = rem >> 6;
    int o = rem & 63;
    float a0 = att[r * 2 + 0], a1 = att[r * 2 + 1];
    const float* b0 = basis + f * EFFD;
    const float* b1 = basis + FF * EFFD + f * EFFD;
    float acc = 0.f;
#pragma unroll 4
    for (int e = 0; e < EFFD; ++e) {
        float w = a0 * b0[e] + a1 * b1[e];
        acc += w * fcw[e * OUTD + o];
    }
    Mt[(size_t)(r * OUTD + o) * FF + f] = f2bf(acc);
}

// ---------------------------------------------------------------------------
// Merged Pass 1: part-blocks (bid < PART_BLOCKS) bucket the edges (blocks
// 0..9 additionally zero the 16 pad rows of one (array, r) region);
// gemm-blocks compute g = bf16((feat @ M) * cj), B-fragments from the
// L2-resident Mt with a 2-deep software-pipelined prefetch, and the MFMA
// operands SWAPPED (A=Mt, B=feat) so each lane's 4 accumulators are 4
// CONSECUTIVE output columns of one row -> ushort4 C-stores.
// ---------------------------------------------------------------------------
union SharedPG {
    struct {
        ushort_t featS[64][136];           // 17.4 KB
    } g;
    struct {
        uint_t stage0[CHUNKE];
        uint_t stage1[CHUNKE];
        int cnt[2 * NBKT];
        int cur[2 * NBKT];
        int gpos[2 * NBKT];
    } p;                                   // 29.7 KB
};

__global__ __launch_bounds__(256, 4) void k_pg(const int* __restrict__ ed,
                                               const int* __restrict__ ei,
                                               int* __restrict__ tails,
                                               uint_t* __restrict__ coarse,
                                               const float* __restrict__ featA,
                                               const float* __restrict__ cjA,
                                               const float* __restrict__ featB,
                                               const float* __restrict__ cjB,
                                               const ushort_t* __restrict__ Mt,
                                               ushort_t* __restrict__ gA,
                                               ushort_t* __restrict__ gB) {
    __shared__ SharedPG sh;
    const int bid = blockIdx.x;
    const int t = threadIdx.x;

    if (bid < PART_BLOCKS) {
        // blocks 0..9: zero the pad rows (rows 50000..50015) of one region
        if (bid < 2 * RR) {
            ushort_t* garr = (bid & 1) ? gB : gA;
            int r = bid >> 1;
            uint_t* z = (uint_t*)(garr + ((size_t)r * NROWP + NDRUG) * OUTD);
            for (int i = t; i < 512; i += 256) z[i] = 0u;
        }

        // ---------------- coarse partition (both dirs per block) -----------
        int chunk = bid & (NCHUNKE - 1);
        int r = bid >> 7;
        const int* A = ed + (size_t)r * EE;   // drug endpoints
        const int* B = ei + (size_t)r * EE;   // disease endpoints
        int* tl0 = tails + (0 * RR + r) * NBKT;
        int* tl1 = tails + (1 * RR + r) * NBKT;
        uint_t* cb0 = coarse + (size_t)(0 * RR + r) * NBKT * CAP;
        uint_t* cb1 = coarse + (size_t)(1 * RR + r) * NBKT * CAP;

        for (int u = t; u < 2 * NBKT; u += 256) { sh.p.cnt[u] = 0; sh.p.cur[u] = 0; }
        __syncthreads();

        int e0 = chunk * CHUNKE;
        for (int i = t; i < CHUNKE; i += 256) {
            int a = __builtin_nontemporal_load(A + e0 + i);
            int b = __builtin_nontemporal_load(B + e0 + i);
            sh.p.stage0[i] = ((uint_t)(b >> 8) << 24) | ((uint_t)(b & 255) << 16) | (uint_t)(ushort_t)a;
            sh.p.stage1[i] = ((uint_t)(a >> 8) << 24) | ((uint_t)(a & 255) << 16) | (uint_t)(ushort_t)b;
            atomicAdd(&sh.p.cnt[b >> 8], 1);
            atomicAdd(&sh.p.cnt[NBKT + (a >> 8)], 1);
        }
        __syncthreads();

        for (int u = t; u < 2 * NBKT; u += 256) {
            int* tl = (u < NBKT) ? tl0 : tl1;
            int bb = (u < NBKT) ? u : u - NBKT;
            sh.p.gpos[u] = atomicAdd(&tl[bb], sh.p.cnt[u]);
        }
        __syncthreads();

        for (int i = t; i < CHUNKE; i += 256) {
            uint_t e = sh.p.stage0[i];
            int b = e >> 24;
            int q = atomicAdd(&sh.p.cur[b], 1);
            int idx = sh.p.gpos[b] + q;
            if (idx < CAP)
                cb0[(size_t)b * CAP + idx] = e & 0x00FFFFFFu;
        }
        for (int i = t; i < CHUNKE; i += 256) {
            uint_t e = sh.p.stage1[i];
            int b = e >> 24;
            int q = atomicAdd(&sh.p.cur[NBKT + b], 1);
            int idx = sh.p.gpos[NBKT + b] + q;
            if (idx < CAP)
                cb1[(size_t)b * CAP + idx] = e & 0x00FFFFFFu;
        }
        return;
    }

    // ---------------- MFMA transform g[r][n][o] -----------------------------
    int gid = bid - PART_BLOCKS;
    int bx = gid % GEMM_RB;
    int qq = gid / GEMM_RB;          // 0..3
    int by = qq & 1;                 // col-half
    int bz = qq >> 1;                // side

    const float* feat; const float* cj; ushort_t* g;
    if (bz == 0) { feat = featA; cj = cjA; g = gA; }
    else         { feat = featB; cj = cjB; g = gB; }

    const int row0 = bx * 64;
    const int ch0  = by * 160;

    for (int i = t; i < 64 * 32; i += 256) {
        int r  = i >> 5;
        int c4 = (i & 31) << 2;
        float4 v = make_float4(0.f, 0.f, 0.f, 0.f);
        int row = row0 + r;
        if (row < NDRUG) v = *(const float4*)(feat + (size_t)row * FF + c4);
        ushort4 pk;
        pk.x = f2bf(v.x); pk.y = f2bf(v.y); pk.z = f2bf(v.z); pk.w = f2bf(v.w);
        *(ushort4*)&sh.g.featS[r][c4] = pk;
    }
    __syncthreads();

    const int w = t >> 6;
    const int l = t & 63;
    const int lr = l & 15;
    const int lg = l >> 4;

    // feat fragment (B-operand after swap): lane holds feat[w*16+lr][ks*32+lg*8..]
    short8 ffrag[4];
#pragma unroll
    for (int ks = 0; ks < 4; ++ks)
        ffrag[ks] = *(const short8*)&sh.g.featS[w * 16 + lr][ks * 32 + lg * 8];

    const int row = row0 + w * 16 + lr;          // fixed output row per lane
    const float cjv = (row < NDRUG) ? cj[row] : 0.f;

    // Mt fragment (A-operand): lane holds Mt[ch0 + n*16 + lr][ks*32 + lg*8..]
    const ushort_t* mtb = Mt + (size_t)(ch0 + lr) * FF + lg * 8;

    // 2-deep software pipeline over n (static ping-pong indexing)
    short8 bf0[4], bf1[4];
#pragma unroll
    for (int ks = 0; ks < 4; ++ks)
        bf0[ks] = *(const short8*)(mtb + ks * 32);

#pragma unroll
    for (int n = 0; n < 10; ++n) {
        const bool even = (n & 1) == 0;
        if (n < 9) {
#pragma unroll
            for (int ks = 0; ks < 4; ++ks) {
                short8 nb = *(const short8*)(mtb + (size_t)(n + 1) * 16 * FF + ks * 32);
                if (even) bf1[ks] = nb; else bf0[ks] = nb;
            }
        }
        f32x4 c = {0.f, 0.f, 0.f, 0.f};
#pragma unroll
        for (int ks = 0; ks < 4; ++ks) {
            short8 a = even ? bf0[ks] : bf1[ks];
            c = __builtin_amdgcn_mfma_f32_16x16x32_bf16(a, ffrag[ks], c, 0, 0, 0);
        }
        // output: lane -> row (fixed), 4 consecutive cols = ch0 + n*16 + lg*4 + 0..3
        int col0 = ch0 + n * 16 + lg * 4;
        int rr = col0 >> 6;
        int oo = col0 & 63;
        if (row < NDRUG) {
            ushort4 pk;
            pk.x = f2bf(c[0] * cjv);
            pk.y = f2bf(c[1] * cjv);
            pk.z = f2bf(c[2] * cjv);
            pk.w = f2bf(c[3] * cjv);
            *(ushort4*)&g[((size_t)rr * NROWP + row) * OUTD + oo] = pk;
        }
    }
}

// ---------------------------------------------------------------------------
// Pass 2 (merged fine-sort + aggregation): one block per coarse bucket.
// Bins padded to multiples of 8 with zero-row sentinels -> predication-free
// aggregation inner loop. XCD-contiguous bucket remap.
// ---------------------------------------------------------------------------
__global__ __launch_bounds__(256) void k_fuse(const ushort_t* __restrict__ gd,
                                              const ushort_t* __restrict__ gi,
                                              const int* __restrict__ tails,
                                              const uint_t* __restrict__ coarse,
                                              const float* __restrict__ ci_drug,
                                              const float* __restrict__ ci_dis,
                                              const float* __restrict__ fcb,
                                              float* __restrict__ out_drug,
                                              float* __restrict__ out_dis) {
    int bid = blockIdx.x;
    int gb = (bid & 7) * (NGB / 8) + (bid >> 3);   // XCD-contiguous range
    int dir = gb / (RR * NBKT);
    int rem = gb - dir * (RR * NBKT);
    int r = rem / NBKT;
    int b = rem - r * NBKT;

    const ushort_t* g = dir ? gi : gd;
    const float* ci   = dir ? ci_drug : ci_dis;
    float* outp       = dir ? out_drug : out_dis;

    const uint_t* cb = coarse + (size_t)gb * CAP;
    int count = tails[gb]; if (count > CAP) count = CAP;

    __shared__ ushort_t lsorted[CAP];   // 8 KB
    __shared__ int hist[256];
    __shared__ int incl[256];           // padded inclusive scan
    __shared__ int cur[256];

    int t = threadIdx.x;

    // register-stage the bucket: one NT read of coarse
    uint_t ereg[16];
#pragma unroll
    for (int k = 0; k < 16; ++k) {
        int i = k * 256 + t;
        ereg[k] = (i < count) ? __builtin_nontemporal_load(cb + i) : 0xFFFFFFFFu;
    }

    hist[t] = 0;
    __syncthreads();
#pragma unroll
    for (int k = 0; k < 16; ++k)
        if (ereg[k] != 0xFFFFFFFFu)
            atomicAdd(&hist[(ereg[k] >> 16) & 255], 1);
    __syncthreads();

    int v = hist[t];
    int p = (v + 7) & ~7;              // bin padded to multiple of 8
    incl[t] = p;
    __syncthreads();
    for (int off = 1; off < 256; off <<= 1) {
        int x = (t >= off) ? incl[t - off] : 0;
        __syncthreads();
        incl[t] += x;
        __syncthreads();
    }
    cur[t] = incl[t] - p;              // padded exclusive start
    __syncthreads();

#pragma unroll
    for (int k = 0; k < 16; ++k) {
        uint_t e = ereg[k];
        if (e != 0xFFFFFFFFu) {
            int pos = atomicAdd(&cur[(e >> 16) & 255], 1);
            if (pos < CAP) lsorted[pos] = (ushort_t)e;
        }
    }
    __syncthreads();

    // fill each bin's pad slots with the zero-row sentinel
    {
        int fe = incl[t]; if (fe > CAP) fe = CAP;
        for (int i = cur[t]; i < fe; ++i) lsorted[i] = (ushort_t)NDRUG;
    }
    __syncthreads();

    // aggregation: wave w -> bins w*64 .. w*64+63 (predication-free)
    const int w       = t >> 6;
    const int lane    = t & 63;
    const int quarter = lane >> 4;
    const int q       = lane & 15;
    const ushort_t* grow = g + (size_t)r * NROWP * OUTD + q * 4;
    const float4 bb = *(const float4*)(fcb + q * 4);

    for (int ib = 0; ib < 64; ++ib) {
        int dstlow = w * 64 + ib;
        int dst = b * 256 + dstlow;
        if (dst >= NDIS) break;
        int start = dstlow ? incl[dstlow - 1] : 0;
        int end = incl[dstlow];
        if (start > CAP) start = CAP;
        if (end > CAP) end = CAP;

        f32x2 a01 = {0.f, 0.f}, a23 = {0.f, 0.f};
        for (int j = start; j < end; j += 8) {
            int s0 = (int)lsorted[j + quarter];
            int s1 = (int)lsorted[j + 4 + quarter];
            uint2 u0 = *(const uint2*)(grow + (size_t)s0 * OUTD);
            uint2 u1 = *(const uint2*)(grow + (size_t)s1 * OUTD);
            f32x2 p0 = { __uint_as_float(u0.x << 16), __uint_as_float(u0.x & 0xffff0000u) };
            f32x2 p1 = { __uint_as_float(u0.y << 16), __uint_as_float(u0.y & 0xffff0000u) };
            f32x2 p2 = { __uint_as_float(u1.x << 16), __uint_as_float(u1.x & 0xffff0000u) };
            f32x2 p3 = { __uint_as_float(u1.y << 16), __uint_as_float(u1.y & 0xffff0000u) };
            a01 += p0; a23 += p1;
            a01 += p2; a23 += p3;
        }
        float a0 = a01.x, a1 = a01.y, a2 = a23.x, a3 = a23.y;
        a0 += __shfl_xor(a0, 16); a1 += __shfl_xor(a1, 16);
        a2 += __shfl_xor(a2, 16); a3 += __shfl_xor(a3, 16);
        a0 += __shfl_xor(a0, 32); a1 += __shfl_xor(a1, 32);
        a2 += __shfl_xor(a2, 32); a3 += __shfl_xor(a3, 32);
        if (quarter == 0) {
            float civ = ci[dst];
            f32x4 o;
            o.x = a0 * civ + bb.x;
            o.y = a1 * civ + bb.y;
            o.z = a2 * civ + bb.z;
            o.w = a3 * civ + bb.w;
            __builtin_nontemporal_store(o,
                (f32x4*)(outp + (size_t)dst * NCOL + r * OUTD + q * 4));
        }
    }
}

// ---------------------------------------------------------------------------
extern "C" void kernel_launch(void* const* d_in, const int* in_sizes, int n_in,
                              void* d_out, int out_size, void* d_ws, size_t ws_size,
                              hipStream_t stream) {
    const float* drug_feat = (const float*)d_in[0];
    const float* dis_feat  = (const float*)d_in[1];
    const float* cj_drug   = (const float*)d_in[2];
    const float* ci_drug   = (const float*)d_in[3];
    const float* cj_dis    = (const float*)d_in[4];
    const float* ci_dis    = (const float*)d_in[5];
    const float* att       = (const float*)d_in[6];
    const float* basis     = (const float*)d_in[7];
    const float* fcw       = (const float*)d_in[8];
    const float* fcb       = (const float*)d_in[9];
    const int*   edge_drug = (const int*)d_in[10];
    const int*   edge_dis  = (const int*)d_in[11];

    float* out      = (float*)d_out;
    float* out_drug = out;
    float* out_dis  = out + (size_t)NDRUG * NCOL;

    // Workspace layout (~96.3 MB):
    //   gd (bf16, [R][50016][64])  32,010,240 @ 0
    //   gi (bf16, [R][50016][64])  32,010,240 @ 32,010,240
    //   Mt (bf16)          163,840 @ 64,020,480
    //   tails (int)          7,840 @ 64,184,320
    //   coarse (u32)    32,112,640 @ 64,192,160
    char* ws = (char*)d_ws;
    ushort_t* gd      = (ushort_t*)ws;
    ushort_t* gi      = (ushort_t*)(ws + 32010240);
    ushort_t* Mtb     = (ushort_t*)(ws + 64020480);
    int*      tails   = (int*)(ws + 64184320);
    uint_t*   coarse  = (uint_t*)(ws + 64192160);

    // zero bucket tails
    hipMemsetAsync(tails, 0, NGB * sizeof(int), stream);

    // A: fused att*basis*fc_w -> Mt bf16 [320][128]
    k_make_M<<<dim3((RR * FF * OUTD + 255) / 256), 256, 0, stream>>>(att, basis, fcw, Mtb);

    // Merged: coarse partition + pad-row zeroing (blocks 0..639) + MFMA transform
    k_pg<<<dim3(PG_BLOCKS), 256, 0, stream>>>(edge_drug, edge_dis, tails, coarse,
                                              drug_feat, cj_drug, dis_feat, cj_dis,
                                              Mtb, gd, gi);

    // Merged fine-sort + gather aggregation + fused ci-scale + bias
    k_fuse<<<dim3(NGB), 256, 0, stream>>>(gd, gi, tails, coarse,
                                          ci_drug, ci_dis, fcb,
                                          out_drug, out_dis);
}

// Round 21
// 188.952 us; speedup vs baseline: 1.0751x; 1.0751x over previous
//
#include <hip/hip_runtime.h>

// Problem constants
#define NDRUG 50000
#define NDIS  50000
#define RR    5
#define FF    128
#define EFFD  128
#define OUTD  64
#define EE    400000
#define NCOL  (RR * OUTD)        // 320 columns in fused OUTPUT layout [n][r*64+o]
#define NEDGE (RR * EE)          // 2,000,000 edges per direction

#define NROWP 50016              // padded rows per rating region (rows 50000..50015 are ZERO)

// Two-level bucket sort
#define NBKT    196              // coarse buckets per (dir,r): dst>>8 (50000/256)
#define CAP     4096             // slot capacity per bucket
#define NGB     (2 * RR * NBKT)  // 1960 global buckets

#define NCHUNKE 128              // edge chunks per r (both dirs handled per block)
#define CHUNKE  (EE / NCHUNKE)   // 3125 edges per chunk (exact)

// merged part+gemm dispatch geometry (gemm: 128 rows/block, 2 row-tiles/wave)
#define PART_BLOCKS (NCHUNKE * RR)            // 640
#define GEMM_RB     ((NDRUG + 127) / 128)     // 391 row-blocks
#define GEMM_BLOCKS (GEMM_RB * 4)             // x2 col-half x2 side = 1564
#define PG_BLOCKS   (PART_BLOCKS + GEMM_BLOCKS)

typedef unsigned short ushort_t;
typedef unsigned int uint_t;
typedef short short8 __attribute__((ext_vector_type(8)));
typedef float f32x4 __attribute__((ext_vector_type(4)));
typedef float f32x2 __attribute__((ext_vector_type(2)));

// f32 -> bf16 round-to-nearest-even
static __device__ __forceinline__ ushort_t f2bf(float f) {
    uint_t u = __float_as_uint(f);
    uint_t r = (u + 0x7FFFu + ((u >> 16) & 1u)) >> 16;
    return (ushort_t)r;
}

// ---------------------------------------------------------------------------
// Kernel A: Mt[col][f] = bf16( sum_e (att[r,0]*basis[0,f,e]+att[r,1]*basis[1,f,e]) * fc_w[e,o] )
// ---------------------------------------------------------------------------
__global__ __launch_bounds__(256) void k_make_M(const float* __restrict__ att,
                                                const float* __restrict__ basis,
                                                const float* __restrict__ fcw,
                                                ushort_t* __restrict__ Mt) {
    int tid = blockIdx.x * 256 + threadIdx.x;
    if (tid >= RR * FF * OUTD) return;
    int r = tid / (FF * OUTD);
    int rem = tid - r * FF * OUTD;
    int f = rem >> 6;
    int o = rem & 63;
    float a0 = att[r * 2 + 0], a1 = att[r * 2 + 1];
    const float* b0 = basis + f * EFFD;
    const float* b1 = basis + FF * EFFD + f * EFFD;
    float acc = 0.f;
#pragma unroll 4
    for (int e = 0; e < EFFD; ++e) {
        float w = a0 * b0[e] + a1 * b1[e];
        acc += w * fcw[e * OUTD + o];
    }
    Mt[(size_t)(r * OUTD + o) * FF + f] = f2bf(acc);
}

// ---------------------------------------------------------------------------
// Merged Pass 1: part-blocks (bid < PART_BLOCKS) bucket the edges (blocks
// 0..9 additionally zero the 16 pad rows of one (array, r) region);
// gemm-blocks compute g = bf16((feat @ M) * cj): 128 rows/block, each wave
// computes TWO row-tiles sharing one Mt ping-pong (A=Mt, B=feat swap ->
// ushort4 C-stores). Mt read from L2 directly.
// ---------------------------------------------------------------------------
union SharedPG {
    struct {
        ushort_t featS[128][136];          // 34.8 KB
    } g;
    struct {
        uint_t stage0[CHUNKE];
        uint_t stage1[CHUNKE];
        int cnt[2 * NBKT];
        int cur[2 * NBKT];
        int gpos[2 * NBKT];
    } p;                                   // 29.7 KB
};

__global__ __launch_bounds__(256, 4) void k_pg(const int* __restrict__ ed,
                                               const int* __restrict__ ei,
                                               int* __restrict__ tails,
                                               uint_t* __restrict__ coarse,
                                               const float* __restrict__ featA,
                                               const float* __restrict__ cjA,
                                               const float* __restrict__ featB,
                                               const float* __restrict__ cjB,
                                               const ushort_t* __restrict__ Mt,
                                               ushort_t* __restrict__ gA,
                                               ushort_t* __restrict__ gB) {
    __shared__ SharedPG sh;
    const int bid = blockIdx.x;
    const int t = threadIdx.x;

    if (bid < PART_BLOCKS) {
        // blocks 0..9: zero the pad rows (rows 50000..50015) of one region
        if (bid < 2 * RR) {
            ushort_t* garr = (bid & 1) ? gB : gA;
            int r = bid >> 1;
            uint_t* z = (uint_t*)(garr + ((size_t)r * NROWP + NDRUG) * OUTD);
            for (int i = t; i < 512; i += 256) z[i] = 0u;
        }

        // ---------------- coarse partition (both dirs per block) -----------
        int chunk = bid & (NCHUNKE - 1);
        int r = bid >> 7;
        const int* A = ed + (size_t)r * EE;   // drug endpoints
        const int* B = ei + (size_t)r * EE;   // disease endpoints
        int* tl0 = tails + (0 * RR + r) * NBKT;
        int* tl1 = tails + (1 * RR + r) * NBKT;
        uint_t* cb0 = coarse + (size_t)(0 * RR + r) * NBKT * CAP;
        uint_t* cb1 = coarse + (size_t)(1 * RR + r) * NBKT * CAP;

        for (int u = t; u < 2 * NBKT; u += 256) { sh.p.cnt[u] = 0; sh.p.cur[u] = 0; }
        __syncthreads();

        int e0 = chunk * CHUNKE;
        for (int i = t; i < CHUNKE; i += 256) {
            int a = __builtin_nontemporal_load(A + e0 + i);
            int b = __builtin_nontemporal_load(B + e0 + i);
            sh.p.stage0[i] = ((uint_t)(b >> 8) << 24) | ((uint_t)(b & 255) << 16) | (uint_t)(ushort_t)a;
            sh.p.stage1[i] = ((uint_t)(a >> 8) << 24) | ((uint_t)(a & 255) << 16) | (uint_t)(ushort_t)b;
            atomicAdd(&sh.p.cnt[b >> 8], 1);
            atomicAdd(&sh.p.cnt[NBKT + (a >> 8)], 1);
        }
        __syncthreads();

        for (int u = t; u < 2 * NBKT; u += 256) {
            int* tl = (u < NBKT) ? tl0 : tl1;
            int bb = (u < NBKT) ? u : u - NBKT;
            sh.p.gpos[u] = atomicAdd(&tl[bb], sh.p.cnt[u]);
        }
        __syncthreads();

        for (int i = t; i < CHUNKE; i += 256) {
            uint_t e = sh.p.stage0[i];
            int b = e >> 24;
            int q = atomicAdd(&sh.p.cur[b], 1);
            int idx = sh.p.gpos[b] + q;
            if (idx < CAP)
                cb0[(size_t)b * CAP + idx] = e & 0x00FFFFFFu;
        }
        for (int i = t; i < CHUNKE; i += 256) {
            uint_t e = sh.p.stage1[i];
            int b = e >> 24;
            int q = atomicAdd(&sh.p.cur[NBKT + b], 1);
            int idx = sh.p.gpos[NBKT + b] + q;
            if (idx < CAP)
                cb1[(size_t)b * CAP + idx] = e & 0x00FFFFFFu;
        }
        return;
    }

    // ---------------- MFMA transform g[r][n][o], 128 rows/block -------------
    int gid = bid - PART_BLOCKS;
    int bx = gid % GEMM_RB;
    int qq = gid / GEMM_RB;          // 0..3
    int by = qq & 1;                 // col-half
    int bz = qq >> 1;                // side

    const float* feat; const float* cj; ushort_t* g;
    if (bz == 0) { feat = featA; cj = cjA; g = gA; }
    else         { feat = featB; cj = cjB; g = gB; }

    const int row0 = bx * 128;
    const int ch0  = by * 160;

    for (int i = t; i < 128 * 32; i += 256) {
        int r  = i >> 5;
        int c4 = (i & 31) << 2;
        float4 v = make_float4(0.f, 0.f, 0.f, 0.f);
        int row = row0 + r;
        if (row < NDRUG) v = *(const float4*)(feat + (size_t)row * FF + c4);
        ushort4 pk;
        pk.x = f2bf(v.x); pk.y = f2bf(v.y); pk.z = f2bf(v.z); pk.w = f2bf(v.w);
        *(ushort4*)&sh.g.featS[r][c4] = pk;
    }
    __syncthreads();

    const int w = t >> 6;
    const int l = t & 63;
    const int lr = l & 15;
    const int lg = l >> 4;

    // two feat fragments (B-operand): rows w*16+lr and 64+w*16+lr
    short8 ffA[4], ffB[4];
#pragma unroll
    for (int ks = 0; ks < 4; ++ks) {
        ffA[ks] = *(const short8*)&sh.g.featS[w * 16 + lr][ks * 32 + lg * 8];
        ffB[ks] = *(const short8*)&sh.g.featS[64 + w * 16 + lr][ks * 32 + lg * 8];
    }

    const int rowA = row0 + w * 16 + lr;
    const int rowB = rowA + 64;
    const float cjvA = (rowA < NDRUG) ? cj[rowA] : 0.f;
    const float cjvB = (rowB < NDRUG) ? cj[rowB] : 0.f;

    // Mt fragment (A-operand): lane holds Mt[ch0 + n*16 + lr][ks*32 + lg*8..]
    const ushort_t* mtb = Mt + (size_t)(ch0 + lr) * FF + lg * 8;

    // 2-deep software pipeline over n (static ping-pong indexing)
    short8 bf0[4], bf1[4];
#pragma unroll
    for (int ks = 0; ks < 4; ++ks)
        bf0[ks] = *(const short8*)(mtb + ks * 32);

#pragma unroll
    for (int n = 0; n < 10; ++n) {
        const bool even = (n & 1) == 0;
        if (n < 9) {
#pragma unroll
            for (int ks = 0; ks < 4; ++ks) {
                short8 nb = *(const short8*)(mtb + (size_t)(n + 1) * 16 * FF + ks * 32);
                if (even) bf1[ks] = nb; else bf0[ks] = nb;
            }
        }
        f32x4 cA = {0.f, 0.f, 0.f, 0.f};
        f32x4 cB = {0.f, 0.f, 0.f, 0.f};
#pragma unroll
        for (int ks = 0; ks < 4; ++ks) {
            short8 a = even ? bf0[ks] : bf1[ks];
            cA = __builtin_amdgcn_mfma_f32_16x16x32_bf16(a, ffA[ks], cA, 0, 0, 0);
            cB = __builtin_amdgcn_mfma_f32_16x16x32_bf16(a, ffB[ks], cB, 0, 0, 0);
        }
        // output: 4 consecutive cols = ch0 + n*16 + lg*4 + 0..3
        int col0 = ch0 + n * 16 + lg * 4;
        int rr = col0 >> 6;
        int oo = col0 & 63;
        if (rowA < NDRUG) {
            ushort4 pk;
            pk.x = f2bf(cA[0] * cjvA);
            pk.y = f2bf(cA[1] * cjvA);
            pk.z = f2bf(cA[2] * cjvA);
            pk.w = f2bf(cA[3] * cjvA);
            *(ushort4*)&g[((size_t)rr * NROWP + rowA) * OUTD + oo] = pk;
        }
        if (rowB < NDRUG) {
            ushort4 pk;
            pk.x = f2bf(cB[0] * cjvB);
            pk.y = f2bf(cB[1] * cjvB);
            pk.z = f2bf(cB[2] * cjvB);
            pk.w = f2bf(cB[3] * cjvB);
            *(ushort4*)&g[((size_t)rr * NROWP + rowB) * OUTD + oo] = pk;
        }
    }
}

// ---------------------------------------------------------------------------
// Pass 2 (merged fine-sort + aggregation): one block per coarse bucket.
// Bins padded to multiples of 8 with zero-row sentinels -> predication-free
// aggregation inner loop. XCD-contiguous bucket remap.
// ---------------------------------------------------------------------------
__global__ __launch_bounds__(256) void k_fuse(const ushort_t* __restrict__ gd,
                                              const ushort_t* __restrict__ gi,
                                              const int* __restrict__ tails,
                                              const uint_t* __restrict__ coarse,
                                              const float* __restrict__ ci_drug,
                                              const float* __restrict__ ci_dis,
                                              const float* __restrict__ fcb,
                                              float* __restrict__ out_drug,
                                              float* __restrict__ out_dis) {
    int bid = blockIdx.x;
    int gb = (bid & 7) * (NGB / 8) + (bid >> 3);   // XCD-contiguous range
    int dir = gb / (RR * NBKT);
    int rem = gb - dir * (RR * NBKT);
    int r = rem / NBKT;
    int b = rem - r * NBKT;

    const ushort_t* g = dir ? gi : gd;
    const float* ci   = dir ? ci_drug : ci_dis;
    float* outp       = dir ? out_drug : out_dis;

    const uint_t* cb = coarse + (size_t)gb * CAP;
    int count = tails[gb]; if (count > CAP) count = CAP;

    __shared__ ushort_t lsorted[CAP];   // 8 KB
    __shared__ int hist[256];
    __shared__ int incl[256];           // padded inclusive scan
    __shared__ int cur[256];

    int t = threadIdx.x;

    // register-stage the bucket: one NT read of coarse
    uint_t ereg[16];
#pragma unroll
    for (int k = 0; k < 16; ++k) {
        int i = k * 256 + t;
        ereg[k] = (i < count) ? __builtin_nontemporal_load(cb + i) : 0xFFFFFFFFu;
    }

    hist[t] = 0;
    __syncthreads();
#pragma unroll
    for (int k = 0; k < 16; ++k)
        if (ereg[k] != 0xFFFFFFFFu)
            atomicAdd(&hist[(ereg[k] >> 16) & 255], 1);
    __syncthreads();

    int v = hist[t];
    int p = (v + 7) & ~7;              // bin padded to multiple of 8
    incl[t] = p;
    __syncthreads();
    for (int off = 1; off < 256; off <<= 1) {
        int x = (t >= off) ? incl[t - off] : 0;
        __syncthreads();
        incl[t] += x;
        __syncthreads();
    }
    cur[t] = incl[t] - p;              // padded exclusive start
    __syncthreads();

#pragma unroll
    for (int k = 0; k < 16; ++k) {
        uint_t e = ereg[k];
        if (e != 0xFFFFFFFFu) {
            int pos = atomicAdd(&cur[(e >> 16) & 255], 1);
            if (pos < CAP) lsorted[pos] = (ushort_t)e;
        }
    }
    __syncthreads();

    // fill each bin's pad slots with the zero-row sentinel
    {
        int fe = incl[t]; if (fe > CAP) fe = CAP;
        for (int i = cur[t]; i < fe; ++i) lsorted[i] = (ushort_t)NDRUG;
    }
    __syncthreads();

    // aggregation: wave w -> bins w*64 .. w*64+63 (predication-free)
    const int w       = t >> 6;
    const int lane    = t & 63;
    const int quarter = lane >> 4;
    const int q       = lane & 15;
    const ushort_t* grow = g + (size_t)r * NROWP * OUTD + q * 4;
    const float4 bb = *(const float4*)(fcb + q * 4);

    for (int ib = 0; ib < 64; ++ib) {
        int dstlow = w * 64 + ib;
        int dst = b * 256 + dstlow;
        if (dst >= NDIS) break;
        int start = dstlow ? incl[dstlow - 1] : 0;
        int end = incl[dstlow];
        if (start > CAP) start = CAP;
        if (end > CAP) end = CAP;

        f32x2 a01 = {0.f, 0.f}, a23 = {0.f, 0.f};
        for (int j = start; j < end; j += 8) {
            int s0 = (int)lsorted[j + quarter];
            int s1 = (int)lsorted[j + 4 + quarter];
            uint2 u0 = *(const uint2*)(grow + (size_t)s0 * OUTD);
            uint2 u1 = *(const uint2*)(grow + (size_t)s1 * OUTD);
            f32x2 p0 = { __uint_as_float(u0.x << 16), __uint_as_float(u0.x & 0xffff0000u) };
            f32x2 p1 = { __uint_as_float(u0.y << 16), __uint_as_float(u0.y & 0xffff0000u) };
            f32x2 p2 = { __uint_as_float(u1.x << 16), __uint_as_float(u1.x & 0xffff0000u) };
            f32x2 p3 = { __uint_as_float(u1.y << 16), __uint_as_float(u1.y & 0xffff0000u) };
            a01 += p0; a23 += p1;
            a01 += p2; a23 += p3;
        }
        float a0 = a01.x, a1 = a01.y, a2 = a23.x, a3 = a23.y;
        a0 += __shfl_xor(a0, 16); a1 += __shfl_xor(a1, 16);
        a2 += __shfl_xor(a2, 16); a3 += __shfl_xor(a3, 16);
        a0 += __shfl_xor(a0, 32); a1 += __shfl_xor(a1, 32);
        a2 += __shfl_xor(a2, 32); a3 += __shfl_xor(a3, 32);
        if (quarter == 0) {
            float civ = ci[dst];
            f32x4 o;
            o.x = a0 * civ + bb.x;
            o.y = a1 * civ + bb.y;
            o.z = a2 * civ + bb.z;
            o.w = a3 * civ + bb.w;
            __builtin_nontemporal_store(o,
                (f32x4*)(outp + (size_t)dst * NCOL + r * OUTD + q * 4));
        }
    }
}

// ---------------------------------------------------------------------------
extern "C" void kernel_launch(void* const* d_in, const int* in_sizes, int n_in,
                              void* d_out, int out_size, void* d_ws, size_t ws_size,
                              hipStream_t stream) {
    const float* drug_feat = (const float*)d_in[0];
    const float* dis_feat  = (const float*)d_in[1];
    const float* cj_drug   = (const float*)d_in[2];
    const float* ci_drug   = (const float*)d_in[3];
    const float* cj_dis    = (const float*)d_in[4];
    const float* ci_dis    = (const float*)d_in[5];
    const float* att       = (const float*)d_in[6];
    const float* basis     = (const float*)d_in[7];
    const float* fcw       = (const float*)d_in[8];
    const float* fcb       = (const float*)d_in[9];
    const int*   edge_drug = (const int*)d_in[10];
    const int*   edge_dis  = (const int*)d_in[11];

    float* out      = (float*)d_out;
    float* out_drug = out;
    float* out_dis  = out + (size_t)NDRUG * NCOL;

    // Workspace layout (~96.3 MB):
    //   gd (bf16, [R][50016][64])  32,010,240 @ 0
    //   gi (bf16, [R][50016][64])  32,010,240 @ 32,010,240
    //   Mt (bf16)          163,840 @ 64,020,480
    //   tails (int)          7,840 @ 64,184,320
    //   coarse (u32)    32,112,640 @ 64,192,160
    char* ws = (char*)d_ws;
    ushort_t* gd      = (ushort_t*)ws;
    ushort_t* gi      = (ushort_t*)(ws + 32010240);
    ushort_t* Mtb     = (ushort_t*)(ws + 64020480);
    int*      tails   = (int*)(ws + 64184320);
    uint_t*   coarse  = (uint_t*)(ws + 64192160);

    // zero bucket tails
    hipMemsetAsync(tails, 0, NGB * sizeof(int), stream);

    // A: fused att*basis*fc_w -> Mt bf16 [320][128]
    k_make_M<<<dim3((RR * FF * OUTD + 255) / 256), 256, 0, stream>>>(att, basis, fcw, Mtb);

    // Merged: coarse partition + pad-row zeroing (blocks 0..639) + MFMA transform
    k_pg<<<dim3(PG_BLOCKS), 256, 0, stream>>>(edge_drug, edge_dis, tails, coarse,
                                              drug_feat, cj_drug, dis_feat, cj_dis,
                                              Mtb, gd, gi);

    // Merged fine-sort + gather aggregation + fused ci-scale + bias
    k_fuse<<<dim3(NGB), 256, 0, stream>>>(gd, gi, tails, coarse,
                                          ci_drug, ci_dis, fcb,
                                          out_drug, out_dis);
}

// Round 22
// 183.363 us; speedup vs baseline: 1.1078x; 1.0305x over previous
//
#include <hip/hip_runtime.h>

// Problem constants
#define NDRUG 50000
#define NDIS  50000
#define RR    5
#define FF    128
#define EFFD  128
#define OUTD  64
#define EE    400000
#define NCOL  (RR * OUTD)        // 320 columns in fused OUTPUT layout [n][r*64+o]
#define NEDGE (RR * EE)          // 2,000,000 edges per direction

#define NROWP 50016              // padded rows per rating region (rows 50000..50015 are ZERO)

// Two-level bucket sort
#define NBKT    196              // coarse buckets per (dir,r): dst>>8 (50000/256)
#define CAP     4096             // slot capacity per bucket
#define NGB     (2 * RR * NBKT)  // 1960 global buckets

#define NCHUNKE 128              // edge chunks per r (both dirs handled per block)
#define CHUNKE  (EE / NCHUNKE)   // 3125 edges per chunk (exact)

// merged part+gemm dispatch geometry (gemm: 128 rows/block, 2 row-tiles/wave)
#define PART_BLOCKS (NCHUNKE * RR)            // 640
#define GEMM_RB     ((NDRUG + 127) / 128)     // 391 row-blocks
#define GEMM_BLOCKS (GEMM_RB * 4)             // x2 col-half x2 side = 1564
#define PG_BLOCKS   (PART_BLOCKS + GEMM_BLOCKS)

typedef unsigned short ushort_t;
typedef unsigned int uint_t;
typedef short short8 __attribute__((ext_vector_type(8)));
typedef float f32x4 __attribute__((ext_vector_type(4)));
typedef float f32x2 __attribute__((ext_vector_type(2)));

// f32 -> bf16 round-to-nearest-even
static __device__ __forceinline__ ushort_t f2bf(float f) {
    uint_t u = __float_as_uint(f);
    uint_t r = (u + 0x7FFFu + ((u >> 16) & 1u)) >> 16;
    return (ushort_t)r;
}

// ---------------------------------------------------------------------------
// Kernel A: Mt[col][f] = bf16( sum_e (att[r,0]*basis[0,f,e]+att[r,1]*basis[1,f,e]) * fc_w[e,o] )
// ---------------------------------------------------------------------------
__global__ __launch_bounds__(256) void k_make_M(const float* __restrict__ att,
                                                const float* __restrict__ basis,
                                                const float* __restrict__ fcw,
                                                ushort_t* __restrict__ Mt) {
    int tid = blockIdx.x * 256 + threadIdx.x;
    if (tid >= RR * FF * OUTD) return;
    int r = tid / (FF * OUTD);
    int rem = tid - r * FF * OUTD;
    int f = rem >> 6;
    int o = rem & 63;
    float a0 = att[r * 2 + 0], a1 = att[r * 2 + 1];
    const float* b0 = basis + f * EFFD;
    const float* b1 = basis + FF * EFFD + f * EFFD;
    float acc = 0.f;
#pragma unroll 4
    for (int e = 0; e < EFFD; ++e) {
        float w = a0 * b0[e] + a1 * b1[e];
        acc += w * fcw[e * OUTD + o];
    }
    Mt[(size_t)(r * OUTD + o) * FF + f] = f2bf(acc);
}

// ---------------------------------------------------------------------------
// Merged Pass 1: part-blocks (bid < PART_BLOCKS) bucket the edges (blocks
// 0..9 additionally zero the 16 pad rows of one (array, r) region);
// gemm-blocks compute g = bf16((feat @ M) * cj): 128 rows/block, 2 row-tiles
// per wave, feat fragments loaded DIRECTLY FROM GLOBAL (converted to bf16 in
// registers) -> NO LDS for the gemm role. Shared block = part role's 29.7 KB
// -> 5 blocks/CU, and gemm waves have no staging barrier.
// ---------------------------------------------------------------------------
__global__ __launch_bounds__(256, 4) void k_pg(const int* __restrict__ ed,
                                               const int* __restrict__ ei,
                                               int* __restrict__ tails,
                                               uint_t* __restrict__ coarse,
                                               const float* __restrict__ featA,
                                               const float* __restrict__ cjA,
                                               const float* __restrict__ featB,
                                               const float* __restrict__ cjB,
                                               const ushort_t* __restrict__ Mt,
                                               ushort_t* __restrict__ gA,
                                               ushort_t* __restrict__ gB) {
    __shared__ uint_t stage0[CHUNKE];
    __shared__ uint_t stage1[CHUNKE];
    __shared__ int cnt[2 * NBKT];
    __shared__ int cur[2 * NBKT];
    __shared__ int gpos[2 * NBKT];

    const int bid = blockIdx.x;
    const int t = threadIdx.x;

    if (bid < PART_BLOCKS) {
        // blocks 0..9: zero the pad rows (rows 50000..50015) of one region
        if (bid < 2 * RR) {
            ushort_t* garr = (bid & 1) ? gB : gA;
            int r = bid >> 1;
            uint_t* z = (uint_t*)(garr + ((size_t)r * NROWP + NDRUG) * OUTD);
            for (int i = t; i < 512; i += 256) z[i] = 0u;
        }

        // ---------------- coarse partition (both dirs per block) -----------
        int chunk = bid & (NCHUNKE - 1);
        int r = bid >> 7;
        const int* A = ed + (size_t)r * EE;   // drug endpoints
        const int* B = ei + (size_t)r * EE;   // disease endpoints
        int* tl0 = tails + (0 * RR + r) * NBKT;
        int* tl1 = tails + (1 * RR + r) * NBKT;
        uint_t* cb0 = coarse + (size_t)(0 * RR + r) * NBKT * CAP;
        uint_t* cb1 = coarse + (size_t)(1 * RR + r) * NBKT * CAP;

        for (int u = t; u < 2 * NBKT; u += 256) { cnt[u] = 0; cur[u] = 0; }
        __syncthreads();

        int e0 = chunk * CHUNKE;
        for (int i = t; i < CHUNKE; i += 256) {
            int a = __builtin_nontemporal_load(A + e0 + i);
            int b = __builtin_nontemporal_load(B + e0 + i);
            stage0[i] = ((uint_t)(b >> 8) << 24) | ((uint_t)(b & 255) << 16) | (uint_t)(ushort_t)a;
            stage1[i] = ((uint_t)(a >> 8) << 24) | ((uint_t)(a & 255) << 16) | (uint_t)(ushort_t)b;
            atomicAdd(&cnt[b >> 8], 1);
            atomicAdd(&cnt[NBKT + (a >> 8)], 1);
        }
        __syncthreads();

        for (int u = t; u < 2 * NBKT; u += 256) {
            int* tl = (u < NBKT) ? tl0 : tl1;
            int bb = (u < NBKT) ? u : u - NBKT;
            gpos[u] = atomicAdd(&tl[bb], cnt[u]);
        }
        __syncthreads();

        for (int i = t; i < CHUNKE; i += 256) {
            uint_t e = stage0[i];
            int b = e >> 24;
            int q = atomicAdd(&cur[b], 1);
            int idx = gpos[b] + q;
            if (idx < CAP)
                cb0[(size_t)b * CAP + idx] = e & 0x00FFFFFFu;
        }
        for (int i = t; i < CHUNKE; i += 256) {
            uint_t e = stage1[i];
            int b = e >> 24;
            int q = atomicAdd(&cur[NBKT + b], 1);
            int idx = gpos[NBKT + b] + q;
            if (idx < CAP)
                cb1[(size_t)b * CAP + idx] = e & 0x00FFFFFFu;
        }
        return;
    }

    // ---------------- MFMA transform g[r][n][o], 128 rows/block, no LDS -----
    int gid = bid - PART_BLOCKS;
    int bx = gid % GEMM_RB;
    int qq = gid / GEMM_RB;          // 0..3
    int by = qq & 1;                 // col-half
    int bz = qq >> 1;                // side

    const float* feat; const float* cj; ushort_t* g;
    if (bz == 0) { feat = featA; cj = cjA; g = gA; }
    else         { feat = featB; cj = cjB; g = gB; }

    const int row0 = bx * 128;
    const int ch0  = by * 160;

    const int w = t >> 6;
    const int l = t & 63;
    const int lr = l & 15;
    const int lg = l >> 4;

    const int rowA = row0 + w * 16 + lr;
    const int rowB = rowA + 64;
    const int rA = rowA < NDRUG ? rowA : NDRUG - 1;   // clamped (reads valid)
    const int rB = rowB < NDRUG ? rowB : NDRUG - 1;
    const float cjvA = (rowA < NDRUG) ? cj[rowA] : 0.f;
    const float cjvB = (rowB < NDRUG) ? cj[rowB] : 0.f;

    // feat fragments direct from global, f32 -> bf16 in registers
    short8 ffA[4], ffB[4];
#pragma unroll
    for (int ks = 0; ks < 4; ++ks) {
        const float* pA = feat + (size_t)rA * FF + ks * 32 + lg * 8;
        const float* pB = feat + (size_t)rB * FF + ks * 32 + lg * 8;
        float4 a0 = *(const float4*)pA;
        float4 a1 = *(const float4*)(pA + 4);
        float4 b0 = *(const float4*)pB;
        float4 b1 = *(const float4*)(pB + 4);
        short8 fa, fb;
        fa[0] = (short)f2bf(a0.x); fa[1] = (short)f2bf(a0.y);
        fa[2] = (short)f2bf(a0.z); fa[3] = (short)f2bf(a0.w);
        fa[4] = (short)f2bf(a1.x); fa[5] = (short)f2bf(a1.y);
        fa[6] = (short)f2bf(a1.z); fa[7] = (short)f2bf(a1.w);
        fb[0] = (short)f2bf(b0.x); fb[1] = (short)f2bf(b0.y);
        fb[2] = (short)f2bf(b0.z); fb[3] = (short)f2bf(b0.w);
        fb[4] = (short)f2bf(b1.x); fb[5] = (short)f2bf(b1.y);
        fb[6] = (short)f2bf(b1.z); fb[7] = (short)f2bf(b1.w);
        ffA[ks] = fa;
        ffB[ks] = fb;
    }

    // Mt fragment (A-operand): lane holds Mt[ch0 + n*16 + lr][ks*32 + lg*8..]
    const ushort_t* mtb = Mt + (size_t)(ch0 + lr) * FF + lg * 8;

    // 2-deep software pipeline over n (static ping-pong indexing)
    short8 bf0[4], bf1[4];
#pragma unroll
    for (int ks = 0; ks < 4; ++ks)
        bf0[ks] = *(const short8*)(mtb + ks * 32);

#pragma unroll
    for (int n = 0; n < 10; ++n) {
        const bool even = (n & 1) == 0;
        if (n < 9) {
#pragma unroll
            for (int ks = 0; ks < 4; ++ks) {
                short8 nb = *(const short8*)(mtb + (size_t)(n + 1) * 16 * FF + ks * 32);
                if (even) bf1[ks] = nb; else bf0[ks] = nb;
            }
        }
        f32x4 cA = {0.f, 0.f, 0.f, 0.f};
        f32x4 cB = {0.f, 0.f, 0.f, 0.f};
#pragma unroll
        for (int ks = 0; ks < 4; ++ks) {
            short8 a = even ? bf0[ks] : bf1[ks];
            cA = __builtin_amdgcn_mfma_f32_16x16x32_bf16(a, ffA[ks], cA, 0, 0, 0);
            cB = __builtin_amdgcn_mfma_f32_16x16x32_bf16(a, ffB[ks], cB, 0, 0, 0);
        }
        // output: 4 consecutive cols = ch0 + n*16 + lg*4 + 0..3
        int col0 = ch0 + n * 16 + lg * 4;
        int rr = col0 >> 6;
        int oo = col0 & 63;
        if (rowA < NDRUG) {
            ushort4 pk;
            pk.x = f2bf(cA[0] * cjvA);
            pk.y = f2bf(cA[1] * cjvA);
            pk.z = f2bf(cA[2] * cjvA);
            pk.w = f2bf(cA[3] * cjvA);
            *(ushort4*)&g[((size_t)rr * NROWP + rowA) * OUTD + oo] = pk;
        }
        if (rowB < NDRUG) {
            ushort4 pk;
            pk.x = f2bf(cB[0] * cjvB);
            pk.y = f2bf(cB[1] * cjvB);
            pk.z = f2bf(cB[2] * cjvB);
            pk.w = f2bf(cB[3] * cjvB);
            *(ushort4*)&g[((size_t)rr * NROWP + rowB) * OUTD + oo] = pk;
        }
    }
}

// ---------------------------------------------------------------------------
// Pass 2 (merged fine-sort + aggregation): one block per coarse bucket.
// Bins padded to multiples of 8 with zero-row sentinels -> predication-free
// aggregation inner loop. XCD-contiguous bucket remap. Block-uniform skips
// on the CAP-sized loops (~half the slots are empty at mean fill 2048).
// ---------------------------------------------------------------------------
__global__ __launch_bounds__(256) void k_fuse(const ushort_t* __restrict__ gd,
                                              const ushort_t* __restrict__ gi,
                                              const int* __restrict__ tails,
                                              const uint_t* __restrict__ coarse,
                                              const float* __restrict__ ci_drug,
                                              const float* __restrict__ ci_dis,
                                              const float* __restrict__ fcb,
                                              float* __restrict__ out_drug,
                                              float* __restrict__ out_dis) {
    int bid = blockIdx.x;
    int gb = (bid & 7) * (NGB / 8) + (bid >> 3);   // XCD-contiguous range
    int dir = gb / (RR * NBKT);
    int rem = gb - dir * (RR * NBKT);
    int r = rem / NBKT;
    int b = rem - r * NBKT;

    const ushort_t* g = dir ? gi : gd;
    const float* ci   = dir ? ci_drug : ci_dis;
    float* outp       = dir ? out_drug : out_dis;

    const uint_t* cb = coarse + (size_t)gb * CAP;
    int count = tails[gb]; if (count > CAP) count = CAP;

    __shared__ ushort_t lsorted[CAP];   // 8 KB
    __shared__ int hist[256];
    __shared__ int incl[256];           // padded inclusive scan
    __shared__ int cur[256];

    int t = threadIdx.x;

    // register-stage the bucket: one NT read of coarse (uniform skip)
    uint_t ereg[16];
#pragma unroll
    for (int k = 0; k < 16; ++k) {
        if (k * 256 < count) {
            int i = k * 256 + t;
            ereg[k] = (i < count) ? __builtin_nontemporal_load(cb + i) : 0xFFFFFFFFu;
        } else {
            ereg[k] = 0xFFFFFFFFu;
        }
    }

    hist[t] = 0;
    __syncthreads();
#pragma unroll
    for (int k = 0; k < 16; ++k) {
        if (k * 256 < count) {
            if (ereg[k] != 0xFFFFFFFFu)
                atomicAdd(&hist[(ereg[k] >> 16) & 255], 1);
        }
    }
    __syncthreads();

    int v = hist[t];
    int p = (v + 7) & ~7;              // bin padded to multiple of 8
    incl[t] = p;
    __syncthreads();
    for (int off = 1; off < 256; off <<= 1) {
        int x = (t >= off) ? incl[t - off] : 0;
        __syncthreads();
        incl[t] += x;
        __syncthreads();
    }
    cur[t] = incl[t] - p;              // padded exclusive start
    __syncthreads();

#pragma unroll
    for (int k = 0; k < 16; ++k) {
        if (k * 256 < count) {
            uint_t e = ereg[k];
            if (e != 0xFFFFFFFFu) {
                int pos = atomicAdd(&cur[(e >> 16) & 255], 1);
                if (pos < CAP) lsorted[pos] = (ushort_t)e;
            }
        }
    }
    __syncthreads();

    // fill each bin's pad slots with the zero-row sentinel
    {
        int fe = incl[t]; if (fe > CAP) fe = CAP;
        for (int i = cur[t]; i < fe; ++i) lsorted[i] = (ushort_t)NDRUG;
    }
    __syncthreads();

    // aggregation: wave w -> bins w*64 .. w*64+63 (predication-free)
    const int w       = t >> 6;
    const int lane    = t & 63;
    const int quarter = lane >> 4;
    const int q       = lane & 15;
    const ushort_t* grow = g + (size_t)r * NROWP * OUTD + q * 4;
    const float4 bb = *(const float4*)(fcb + q * 4);

    for (int ib = 0; ib < 64; ++ib) {
        int dstlow = w * 64 + ib;
        int dst = b * 256 + dstlow;
        if (dst >= NDIS) break;
        int start = dstlow ? incl[dstlow - 1] : 0;
        int end = incl[dstlow];
        if (start > CAP) start = CAP;
        if (end > CAP) end = CAP;

        f32x2 a01 = {0.f, 0.f}, a23 = {0.f, 0.f};
        for (int j = start; j < end; j += 8) {
            int s0 = (int)lsorted[j + quarter];
            int s1 = (int)lsorted[j + 4 + quarter];
            uint2 u0 = *(const uint2*)(grow + (size_t)s0 * OUTD);
            uint2 u1 = *(const uint2*)(grow + (size_t)s1 * OUTD);
            f32x2 p0 = { __uint_as_float(u0.x << 16), __uint_as_float(u0.x & 0xffff0000u) };
            f32x2 p1 = { __uint_as_float(u0.y << 16), __uint_as_float(u0.y & 0xffff0000u) };
            f32x2 p2 = { __uint_as_float(u1.x << 16), __uint_as_float(u1.x & 0xffff0000u) };
            f32x2 p3 = { __uint_as_float(u1.y << 16), __uint_as_float(u1.y & 0xffff0000u) };
            a01 += p0; a23 += p1;
            a01 += p2; a23 += p3;
        }
        float a0 = a01.x, a1 = a01.y, a2 = a23.x, a3 = a23.y;
        a0 += __shfl_xor(a0, 16); a1 += __shfl_xor(a1, 16);
        a2 += __shfl_xor(a2, 16); a3 += __shfl_xor(a3, 16);
        a0 += __shfl_xor(a0, 32); a1 += __shfl_xor(a1, 32);
        a2 += __shfl_xor(a2, 32); a3 += __shfl_xor(a3, 32);
        if (quarter == 0) {
            float civ = ci[dst];
            f32x4 o;
            o.x = a0 * civ + bb.x;
            o.y = a1 * civ + bb.y;
            o.z = a2 * civ + bb.z;
            o.w = a3 * civ + bb.w;
            __builtin_nontemporal_store(o,
                (f32x4*)(outp + (size_t)dst * NCOL + r * OUTD + q * 4));
        }
    }
}

// ---------------------------------------------------------------------------
extern "C" void kernel_launch(void* const* d_in, const int* in_sizes, int n_in,
                              void* d_out, int out_size, void* d_ws, size_t ws_size,
                              hipStream_t stream) {
    const float* drug_feat = (const float*)d_in[0];
    const float* dis_feat  = (const float*)d_in[1];
    const float* cj_drug   = (const float*)d_in[2];
    const float* ci_drug   = (const float*)d_in[3];
    const float* cj_dis    = (const float*)d_in[4];
    const float* ci_dis    = (const float*)d_in[5];
    const float* att       = (const float*)d_in[6];
    const float* basis     = (const float*)d_in[7];
    const float* fcw       = (const float*)d_in[8];
    const float* fcb       = (const float*)d_in[9];
    const int*   edge_drug = (const int*)d_in[10];
    const int*   edge_dis  = (const int*)d_in[11];

    float* out      = (float*)d_out;
    float* out_drug = out;
    float* out_dis  = out + (size_t)NDRUG * NCOL;

    // Workspace layout (~96.3 MB):
    //   gd (bf16, [R][50016][64])  32,010,240 @ 0
    //   gi (bf16, [R][50016][64])  32,010,240 @ 32,010,240
    //   Mt (bf16)          163,840 @ 64,020,480
    //   tails (int)          7,840 @ 64,184,320
    //   coarse (u32)    32,112,640 @ 64,192,160
    char* ws = (char*)d_ws;
    ushort_t* gd      = (ushort_t*)ws;
    ushort_t* gi      = (ushort_t*)(ws + 32010240);
    ushort_t* Mtb     = (ushort_t*)(ws + 64020480);
    int*      tails   = (int*)(ws + 64184320);
    uint_t*   coarse  = (uint_t*)(ws + 64192160);

    // zero bucket tails
    hipMemsetAsync(tails, 0, NGB * sizeof(int), stream);

    // A: fused att*basis*fc_w -> Mt bf16 [320][128]
    k_make_M<<<dim3((RR * FF * OUTD + 255) / 256), 256, 0, stream>>>(att, basis, fcw, Mtb);

    // Merged: coarse partition + pad-row zeroing (blocks 0..639) + MFMA transform
    k_pg<<<dim3(PG_BLOCKS), 256, 0, stream>>>(edge_drug, edge_dis, tails, coarse,
                                              drug_feat, cj_drug, dis_feat, cj_dis,
                                              Mtb, gd, gi);

    // Merged fine-sort + gather aggregation + fused ci-scale + bias
    k_fuse<<<dim3(NGB), 256, 0, stream>>>(gd, gi, tails, coarse,
                                          ci_drug, ci_dis, fcb,
                                          out_drug, out_dis);
}

// Round 23
// 168.436 us; speedup vs baseline: 1.2060x; 1.0886x over previous
//
#include <hip/hip_runtime.h>

// Problem constants
#define NDRUG 50000
#define NDIS  50000
#define RR    5
#define FF    128
#define EFFD  128
#define OUTD  64
#define EE    400000
#define NCOL  (RR * OUTD)        // 320 columns in fused OUTPUT layout [n][r*64+o]
#define NEDGE (RR * EE)          // 2,000,000 edges per direction

#define NROWP 50016              // padded rows per rating region (rows 50000..50015 are ZERO)

// Two-level bucket sort
#define NBKT    196              // coarse buckets per (dir,r): dst>>8 (50000/256)
#define CAP     4096             // slot capacity per bucket
#define NGB     (2 * RR * NBKT)  // 1960 global buckets

#define NCHUNKE 128              // edge chunks per r (both dirs handled per block)
#define CHUNKE  (EE / NCHUNKE)   // 3125 edges per chunk (exact)

// merged part+gemm dispatch geometry (gemm: 128 rows/block, 2 row-tiles/wave)
#define PART_BLOCKS (NCHUNKE * RR)            // 640
#define GEMM_RB     ((NDRUG + 127) / 128)     // 391 row-blocks
#define GEMM_BLOCKS (GEMM_RB * 4)             // x2 col-half x2 side = 1564
#define PG_BLOCKS   (PART_BLOCKS + GEMM_BLOCKS)

typedef unsigned short ushort_t;
typedef unsigned int uint_t;
typedef short short8 __attribute__((ext_vector_type(8)));
typedef float f32x4 __attribute__((ext_vector_type(4)));
typedef float f32x2 __attribute__((ext_vector_type(2)));

// f32 -> bf16 round-to-nearest-even
static __device__ __forceinline__ ushort_t f2bf(float f) {
    uint_t u = __float_as_uint(f);
    uint_t r = (u + 0x7FFFu + ((u >> 16) & 1u)) >> 16;
    return (ushort_t)r;
}

// ---------------------------------------------------------------------------
// Kernel A: Mt[col][f] = bf16( sum_e (att[r,0]*basis[0,f,e]+att[r,1]*basis[1,f,e]) * fc_w[e,o] )
// ---------------------------------------------------------------------------
__global__ __launch_bounds__(256) void k_make_M(const float* __restrict__ att,
                                                const float* __restrict__ basis,
                                                const float* __restrict__ fcw,
                                                ushort_t* __restrict__ Mt) {
    int tid = blockIdx.x * 256 + threadIdx.x;
    if (tid >= RR * FF * OUTD) return;
    int r = tid / (FF * OUTD);
    int rem = tid - r * FF * OUTD;
    int f = rem >> 6;
    int o = rem & 63;
    float a0 = att[r * 2 + 0], a1 = att[r * 2 + 1];
    const float* b0 = basis + f * EFFD;
    const float* b1 = basis + FF * EFFD + f * EFFD;
    float acc = 0.f;
#pragma unroll 4
    for (int e = 0; e < EFFD; ++e) {
        float w = a0 * b0[e] + a1 * b1[e];
        acc += w * fcw[e * OUTD + o];
    }
    Mt[(size_t)(r * OUTD + o) * FF + f] = f2bf(acc);
}

// ---------------------------------------------------------------------------
// Merged Pass 1: part-blocks (bid < PART_BLOCKS) bucket the edges (blocks
// 0..9 additionally zero the 16 pad rows of one (array, r) region);
// gemm-blocks compute g = bf16((feat @ M) * cj): 128 rows/block, 2 row-tiles
// per wave, feat fragments loaded directly from global (bf16 in registers),
// no LDS for the gemm role.
// ---------------------------------------------------------------------------
__global__ __launch_bounds__(256, 4) void k_pg(const int* __restrict__ ed,
                                               const int* __restrict__ ei,
                                               int* __restrict__ tails,
                                               uint_t* __restrict__ coarse,
                                               const float* __restrict__ featA,
                                               const float* __restrict__ cjA,
                                               const float* __restrict__ featB,
                                               const float* __restrict__ cjB,
                                               const ushort_t* __restrict__ Mt,
                                               ushort_t* __restrict__ gA,
                                               ushort_t* __restrict__ gB) {
    __shared__ uint_t stage0[CHUNKE];
    __shared__ uint_t stage1[CHUNKE];
    __shared__ int cnt[2 * NBKT];
    __shared__ int cur[2 * NBKT];
    __shared__ int gpos[2 * NBKT];

    const int bid = blockIdx.x;
    const int t = threadIdx.x;

    if (bid < PART_BLOCKS) {
        // blocks 0..9: zero the pad rows (rows 50000..50015) of one region
        if (bid < 2 * RR) {
            ushort_t* garr = (bid & 1) ? gB : gA;
            int r = bid >> 1;
            uint_t* z = (uint_t*)(garr + ((size_t)r * NROWP + NDRUG) * OUTD);
            for (int i = t; i < 512; i += 256) z[i] = 0u;
        }

        // ---------------- coarse partition (both dirs per block) -----------
        int chunk = bid & (NCHUNKE - 1);
        int r = bid >> 7;
        const int* A = ed + (size_t)r * EE;   // drug endpoints
        const int* B = ei + (size_t)r * EE;   // disease endpoints
        int* tl0 = tails + (0 * RR + r) * NBKT;
        int* tl1 = tails + (1 * RR + r) * NBKT;
        uint_t* cb0 = coarse + (size_t)(0 * RR + r) * NBKT * CAP;
        uint_t* cb1 = coarse + (size_t)(1 * RR + r) * NBKT * CAP;

        for (int u = t; u < 2 * NBKT; u += 256) { cnt[u] = 0; cur[u] = 0; }
        __syncthreads();

        int e0 = chunk * CHUNKE;
        for (int i = t; i < CHUNKE; i += 256) {
            int a = __builtin_nontemporal_load(A + e0 + i);
            int b = __builtin_nontemporal_load(B + e0 + i);
            stage0[i] = ((uint_t)(b >> 8) << 24) | ((uint_t)(b & 255) << 16) | (uint_t)(ushort_t)a;
            stage1[i] = ((uint_t)(a >> 8) << 24) | ((uint_t)(a & 255) << 16) | (uint_t)(ushort_t)b;
            atomicAdd(&cnt[b >> 8], 1);
            atomicAdd(&cnt[NBKT + (a >> 8)], 1);
        }
        __syncthreads();

        for (int u = t; u < 2 * NBKT; u += 256) {
            int* tl = (u < NBKT) ? tl0 : tl1;
            int bb = (u < NBKT) ? u : u - NBKT;
            gpos[u] = atomicAdd(&tl[bb], cnt[u]);
        }
        __syncthreads();

        for (int i = t; i < CHUNKE; i += 256) {
            uint_t e = stage0[i];
            int b = e >> 24;
            int q = atomicAdd(&cur[b], 1);
            int idx = gpos[b] + q;
            if (idx < CAP)
                cb0[(size_t)b * CAP + idx] = e & 0x00FFFFFFu;
        }
        for (int i = t; i < CHUNKE; i += 256) {
            uint_t e = stage1[i];
            int b = e >> 24;
            int q = atomicAdd(&cur[NBKT + b], 1);
            int idx = gpos[NBKT + b] + q;
            if (idx < CAP)
                cb1[(size_t)b * CAP + idx] = e & 0x00FFFFFFu;
        }
        return;
    }

    // ---------------- MFMA transform g[r][n][o], 128 rows/block, no LDS -----
    int gid = bid - PART_BLOCKS;
    int bx = gid % GEMM_RB;
    int qq = gid / GEMM_RB;          // 0..3
    int by = qq & 1;                 // col-half
    int bz = qq >> 1;                // side

    const float* feat; const float* cj; ushort_t* g;
    if (bz == 0) { feat = featA; cj = cjA; g = gA; }
    else         { feat = featB; cj = cjB; g = gB; }

    const int row0 = bx * 128;
    const int ch0  = by * 160;

    const int w = t >> 6;
    const int l = t & 63;
    const int lr = l & 15;
    const int lg = l >> 4;

    const int rowA = row0 + w * 16 + lr;
    const int rowB = rowA + 64;
    const int rA = rowA < NDRUG ? rowA : NDRUG - 1;   // clamped (reads valid)
    const int rB = rowB < NDRUG ? rowB : NDRUG - 1;
    const float cjvA = (rowA < NDRUG) ? cj[rowA] : 0.f;
    const float cjvB = (rowB < NDRUG) ? cj[rowB] : 0.f;

    // feat fragments direct from global, f32 -> bf16 in registers
    short8 ffA[4], ffB[4];
#pragma unroll
    for (int ks = 0; ks < 4; ++ks) {
        const float* pA = feat + (size_t)rA * FF + ks * 32 + lg * 8;
        const float* pB = feat + (size_t)rB * FF + ks * 32 + lg * 8;
        float4 a0 = *(const float4*)pA;
        float4 a1 = *(const float4*)(pA + 4);
        float4 b0 = *(const float4*)pB;
        float4 b1 = *(const float4*)(pB + 4);
        short8 fa, fb;
        fa[0] = (short)f2bf(a0.x); fa[1] = (short)f2bf(a0.y);
        fa[2] = (short)f2bf(a0.z); fa[3] = (short)f2bf(a0.w);
        fa[4] = (short)f2bf(a1.x); fa[5] = (short)f2bf(a1.y);
        fa[6] = (short)f2bf(a1.z); fa[7] = (short)f2bf(a1.w);
        fb[0] = (short)f2bf(b0.x); fb[1] = (short)f2bf(b0.y);
        fb[2] = (short)f2bf(b0.z); fb[3] = (short)f2bf(b0.w);
        fb[4] = (short)f2bf(b1.x); fb[5] = (short)f2bf(b1.y);
        fb[6] = (short)f2bf(b1.z); fb[7] = (short)f2bf(b1.w);
        ffA[ks] = fa;
        ffB[ks] = fb;
    }

    // Mt fragment (A-operand): lane holds Mt[ch0 + n*16 + lr][ks*32 + lg*8..]
    const ushort_t* mtb = Mt + (size_t)(ch0 + lr) * FF + lg * 8;

    // 2-deep software pipeline over n (static ping-pong indexing)
    short8 bf0[4], bf1[4];
#pragma unroll
    for (int ks = 0; ks < 4; ++ks)
        bf0[ks] = *(const short8*)(mtb + ks * 32);

#pragma unroll
    for (int n = 0; n < 10; ++n) {
        const bool even = (n & 1) == 0;
        if (n < 9) {
#pragma unroll
            for (int ks = 0; ks < 4; ++ks) {
                short8 nb = *(const short8*)(mtb + (size_t)(n + 1) * 16 * FF + ks * 32);
                if (even) bf1[ks] = nb; else bf0[ks] = nb;
            }
        }
        f32x4 cA = {0.f, 0.f, 0.f, 0.f};
        f32x4 cB = {0.f, 0.f, 0.f, 0.f};
#pragma unroll
        for (int ks = 0; ks < 4; ++ks) {
            short8 a = even ? bf0[ks] : bf1[ks];
            cA = __builtin_amdgcn_mfma_f32_16x16x32_bf16(a, ffA[ks], cA, 0, 0, 0);
            cB = __builtin_amdgcn_mfma_f32_16x16x32_bf16(a, ffB[ks], cB, 0, 0, 0);
        }
        // output: 4 consecutive cols = ch0 + n*16 + lg*4 + 0..3
        int col0 = ch0 + n * 16 + lg * 4;
        int rr = col0 >> 6;
        int oo = col0 & 63;
        if (rowA < NDRUG) {
            ushort4 pk;
            pk.x = f2bf(cA[0] * cjvA);
            pk.y = f2bf(cA[1] * cjvA);
            pk.z = f2bf(cA[2] * cjvA);
            pk.w = f2bf(cA[3] * cjvA);
            *(ushort4*)&g[((size_t)rr * NROWP + rowA) * OUTD + oo] = pk;
        }
        if (rowB < NDRUG) {
            ushort4 pk;
            pk.x = f2bf(cB[0] * cjvB);
            pk.y = f2bf(cB[1] * cjvB);
            pk.z = f2bf(cB[2] * cjvB);
            pk.w = f2bf(cB[3] * cjvB);
            *(ushort4*)&g[((size_t)rr * NROWP + rowB) * OUTD + oo] = pk;
        }
    }
}

// ---------------------------------------------------------------------------
// Pass 2 (merged fine-sort + aggregation): one block per coarse bucket.
// QUARTER-PER-BIN aggregation: each 16-lane quarter owns one bin (16 lanes x
// uint2 = all 64 cols), accumulating serially -> NO cross-lane reduce, no
// bin padding, direct per-quarter float4 stores. Loop bound = wave-max of
// the 4 quarter bin-lengths (2 shfl_xor); inactive steps masked by cndmask.
// ---------------------------------------------------------------------------
__global__ __launch_bounds__(256) void k_fuse(const ushort_t* __restrict__ gd,
                                              const ushort_t* __restrict__ gi,
                                              const int* __restrict__ tails,
                                              const uint_t* __restrict__ coarse,
                                              const float* __restrict__ ci_drug,
                                              const float* __restrict__ ci_dis,
                                              const float* __restrict__ fcb,
                                              float* __restrict__ out_drug,
                                              float* __restrict__ out_dis) {
    int bid = blockIdx.x;
    int gb = (bid & 7) * (NGB / 8) + (bid >> 3);   // XCD-contiguous range
    int dir = gb / (RR * NBKT);
    int rem = gb - dir * (RR * NBKT);
    int r = rem / NBKT;
    int b = rem - r * NBKT;

    const ushort_t* g = dir ? gi : gd;
    const float* ci   = dir ? ci_drug : ci_dis;
    float* outp       = dir ? out_drug : out_dis;

    const uint_t* cb = coarse + (size_t)gb * CAP;
    int count = tails[gb]; if (count > CAP) count = CAP;

    __shared__ ushort_t lsorted[CAP];   // 8 KB
    __shared__ int hist[256];
    __shared__ int incl[256];           // plain inclusive scan (no padding)
    __shared__ int cur[256];

    int t = threadIdx.x;

    // register-stage the bucket: one NT read of coarse (uniform skip)
    uint_t ereg[16];
#pragma unroll
    for (int k = 0; k < 16; ++k) {
        if (k * 256 < count) {
            int i = k * 256 + t;
            ereg[k] = (i < count) ? __builtin_nontemporal_load(cb + i) : 0xFFFFFFFFu;
        } else {
            ereg[k] = 0xFFFFFFFFu;
        }
    }

    hist[t] = 0;
    __syncthreads();
#pragma unroll
    for (int k = 0; k < 16; ++k) {
        if (k * 256 < count) {
            if (ereg[k] != 0xFFFFFFFFu)
                atomicAdd(&hist[(ereg[k] >> 16) & 255], 1);
        }
    }
    __syncthreads();

    int v = hist[t];
    incl[t] = v;
    __syncthreads();
    for (int off = 1; off < 256; off <<= 1) {
        int x = (t >= off) ? incl[t - off] : 0;
        __syncthreads();
        incl[t] += x;
        __syncthreads();
    }
    cur[t] = incl[t] - v;              // exclusive start
    __syncthreads();

#pragma unroll
    for (int k = 0; k < 16; ++k) {
        if (k * 256 < count) {
            uint_t e = ereg[k];
            if (e != 0xFFFFFFFFu) {
                int pos = atomicAdd(&cur[(e >> 16) & 255], 1);
                if (pos < CAP) lsorted[pos] = (ushort_t)e;
            }
        }
    }
    __syncthreads();

    // aggregation: wave w -> bins w*64..w*64+63, 4 at a time (1 per quarter)
    const int w       = t >> 6;
    const int lane    = t & 63;
    const int quarter = lane >> 4;
    const int q       = lane & 15;
    const ushort_t* grow = g + (size_t)r * NROWP * OUTD + q * 4;
    const float4 bb = *(const float4*)(fcb + q * 4);

    for (int ib = 0; ib < 16; ++ib) {
        int dstlow = w * 64 + ib * 4 + quarter;   // this quarter's bin
        int dst = b * 256 + dstlow;
        int start = dstlow ? incl[dstlow - 1] : 0;
        int end   = incl[dstlow];
        int len   = end - start;
        int lenm1 = len > 0 ? len - 1 : 0;

        // loop bound = max over the 4 quarters in this wave
        int wm = len;
        wm = max(wm, __shfl_xor(wm, 16));
        wm = max(wm, __shfl_xor(wm, 32));

        f32x2 a01 = {0.f, 0.f}, a23 = {0.f, 0.f};
        for (int s = 0; s < wm; ++s) {
            int so  = s < lenm1 ? s : lenm1;
            int idx = start + so;
            if (idx >= CAP) idx = CAP - 1;
            int sj = (int)lsorted[idx];
            uint2 u0 = *(const uint2*)(grow + (size_t)sj * OUTD);
            bool act = s < len;
            uint_t ux = act ? u0.x : 0u;
            uint_t uy = act ? u0.y : 0u;
            f32x2 p0 = { __uint_as_float(ux << 16), __uint_as_float(ux & 0xffff0000u) };
            f32x2 p1 = { __uint_as_float(uy << 16), __uint_as_float(uy & 0xffff0000u) };
            a01 += p0;
            a23 += p1;
        }
        if (dst < NDIS) {
            float civ = ci[dst];
            f32x4 o;
            o.x = a01.x * civ + bb.x;
            o.y = a01.y * civ + bb.y;
            o.z = a23.x * civ + bb.z;
            o.w = a23.y * civ + bb.w;
            __builtin_nontemporal_store(o,
                (f32x4*)(outp + (size_t)dst * NCOL + r * OUTD + q * 4));
        }
    }
}

// ---------------------------------------------------------------------------
extern "C" void kernel_launch(void* const* d_in, const int* in_sizes, int n_in,
                              void* d_out, int out_size, void* d_ws, size_t ws_size,
                              hipStream_t stream) {
    const float* drug_feat = (const float*)d_in[0];
    const float* dis_feat  = (const float*)d_in[1];
    const float* cj_drug   = (const float*)d_in[2];
    const float* ci_drug   = (const float*)d_in[3];
    const float* cj_dis    = (const float*)d_in[4];
    const float* ci_dis    = (const float*)d_in[5];
    const float* att       = (const float*)d_in[6];
    const float* basis     = (const float*)d_in[7];
    const float* fcw       = (const float*)d_in[8];
    const float* fcb       = (const float*)d_in[9];
    const int*   edge_drug = (const int*)d_in[10];
    const int*   edge_dis  = (const int*)d_in[11];

    float* out      = (float*)d_out;
    float* out_drug = out;
    float* out_dis  = out + (size_t)NDRUG * NCOL;

    // Workspace layout (~96.3 MB):
    //   gd (bf16, [R][50016][64])  32,010,240 @ 0
    //   gi (bf16, [R][50016][64])  32,010,240 @ 32,010,240
    //   Mt (bf16)          163,840 @ 64,020,480
    //   tails (int)          7,840 @ 64,184,320
    //   coarse (u32)    32,112,640 @ 64,192,160
    char* ws = (char*)d_ws;
    ushort_t* gd      = (ushort_t*)ws;
    ushort_t* gi      = (ushort_t*)(ws + 32010240);
    ushort_t* Mtb     = (ushort_t*)(ws + 64020480);
    int*      tails   = (int*)(ws + 64184320);
    uint_t*   coarse  = (uint_t*)(ws + 64192160);

    // zero bucket tails
    hipMemsetAsync(tails, 0, NGB * sizeof(int), stream);

    // A: fused att*basis*fc_w -> Mt bf16 [320][128]
    k_make_M<<<dim3((RR * FF * OUTD + 255) / 256), 256, 0, stream>>>(att, basis, fcw, Mtb);

    // Merged: coarse partition + pad-row zeroing (blocks 0..639) + MFMA transform
    k_pg<<<dim3(PG_BLOCKS), 256, 0, stream>>>(edge_drug, edge_dis, tails, coarse,
                                              drug_feat, cj_drug, dis_feat, cj_dis,
                                              Mtb, gd, gi);

    // Merged fine-sort + quarter-per-bin aggregation + fused ci-scale + bias
    k_fuse<<<dim3(NGB), 256, 0, stream>>>(gd, gi, tails, coarse,
                                          ci_drug, ci_dis, fcb,
                                          out_drug, out_dis);
}